// Round 12
// baseline (29.266 us; speedup 1.0000x reference)
//
#include <hip/hip_runtime.h>
#include <math.h>

// Forward kinematics, 6-joint DH chain, B=1048576.
// R12: occupancy attack. Evidence: R11 halved hot-path instructions -> 0 delta
// (22.8 vs 22.7us) => latency-bound, not issue-bound. VGPR ~92 (forced by the
// in-kernel f64 fixup's 23 live doubles) caps residency at ~5 waves/SIMD.
// Split with ZERO collection overhead (R8's LDS+barrier tail cost ~10us):
//   fk6_hot : pure f32, NO f64 code, NO barrier, NO atomics. Risky lanes ->
//             __ballot, lane0 stores one u64/wave (always written, no init).
//   fk6_fixb: scans 16384 wave masks, f64-redoes set bits (~100 elems).
// Fallback: R11-style combined kernel if ws too small.

#define RAD_D  (3.141592653589793 / 180.0)
#define RAD_F  0.017453292519943295f
#define DEG_F  57.29577951308232f
#define TINY_D 1e-6

// ---------- f64 sincos of degrees (Cephes, ~1ulp) ----------
__device__ __forceinline__ void sincos_deg(double xdeg, double* s, double* c)
{
    const double qf = rint(xdeg * (1.0 / 90.0));
    const double r  = fma(qf, -90.0, xdeg) * RAD_D;
    const int q = ((int)qf) & 3;
    const double z = r * r;

    double sp = 1.58962301576546568060e-10;
    sp = fma(sp, z, -2.50507477628578072866e-8);
    sp = fma(sp, z,  2.75573136213857245213e-6);
    sp = fma(sp, z, -1.98412698295895385996e-4);
    sp = fma(sp, z,  8.33333333332211858878e-3);
    sp = fma(sp, z, -1.66666666666666307295e-1);
    const double sr = fma(r * z, sp, r);

    double cp = -1.13585365213876817300e-11;
    cp = fma(cp, z,  2.08757008419747316778e-9);
    cp = fma(cp, z, -2.75573141792967388112e-7);
    cp = fma(cp, z,  2.48015872888517179954e-5);
    cp = fma(cp, z, -1.38888888888730564116e-3);
    cp = fma(cp, z,  4.16666666666665929218e-2);
    const double cr = fma(z * z, cp, fma(z, -0.5, 1.0));

    double ss = (q & 1) ? cr : sr;
    double cc = (q & 1) ? sr : cr;
    ss = (q & 2)       ? -ss : ss;
    cc = ((q + 1) & 2) ? -cc : cc;
    *s = ss; *c = cc;
}

// ---------- f32 sincos of degrees ----------
__device__ __forceinline__ void sincosf_deg(float xdeg, float* s, float* c)
{
    const float qf = rintf(xdeg * (1.0f / 90.0f));
    const float r  = fmaf(qf, -90.0f, xdeg) * RAD_F;
    const int q = ((int)qf) & 3;
    const float z = r * r;

    float sp = -1.9515295891e-4f;
    sp = fmaf(sp, z,  8.3321608736e-3f);
    sp = fmaf(sp, z, -1.6666654611e-1f);
    const float sr = fmaf(r * z, sp, r);

    float cp =  2.443315711809948e-5f;
    cp = fmaf(cp, z, -1.388731625493765e-3f);
    cp = fmaf(cp, z,  4.166664568298827e-2f);
    const float cr = fmaf(z * z, cp, fmaf(z, -0.5f, 1.0f));

    float ss = (q & 1) ? cr : sr;
    float cc = (q & 1) ? sr : cr;
    ss = (q & 2)       ? -ss : ss;
    cc = ((q + 1) & 2) ? -cc : cc;
    *s = ss; *c = cc;
}

// ---------- f32 atan2 in DEGREES (poly + hw rcp) ----------
__device__ __forceinline__ float atan2_deg(float y, float x)
{
    const float ay = fabsf(y), ax = fabsf(x);
    const float mn = fminf(ay, ax), mx = fmaxf(ay, ax);
    const float r  = mn * __builtin_amdgcn_rcpf(mx);
    const float z  = r * r;
    float p = -0.671575f;
    p = fmaf(p, z,  3.016813f);
    p = fmaf(p, z, -6.671107f);
    p = fmaf(p, z, 11.089241f);
    p = fmaf(p, z, -19.057917f);
    p = fmaf(p, z, 57.294477f);
    float a = r * p;
    a = (ay > ax)   ? 90.0f  - a : a;
    a = (x < 0.0f)  ? 180.0f - a : a;
    return copysignf(a, y);
}

// ---------- shared f32 compute: res[6] + risky flag ----------
struct DHF32 { float a[6], ca[6], sa[6], nsd[6], cd[6], th0[6]; int spec; };

__device__ __forceinline__ void fk_hot(const float thf[6], const DHF32& K,
                                       float res[6], bool& risky)
{
    if (K.spec) {
        float st[6], ct[6];
        #pragma unroll
        for (int i = 0; i < 6; ++i)
            sincosf_deg(thf[i], &st[i], &ct[i]);

        // M = T0*T1 closed form. T0: a=0,alpha=180,d=-650; T1: a=270,alpha=90,d=0.
        float M[3][4];
        M[0][0] =  ct[0]*ct[1];  M[0][1] = -ct[0]*st[1];  M[0][2] = st[0];  M[0][3] =  270.0f*ct[0];
        M[1][0] = -st[0]*ct[1];  M[1][1] =  st[0]*st[1];  M[1][2] = ct[0];  M[1][3] = -270.0f*st[0];
        M[2][0] = -st[1];        M[2][1] = -ct[1];        M[2][2] = 0.0f;   M[2][3] =  650.0f;

        // T2: alpha=0, a=800, d=0
        #pragma unroll
        for (int r = 0; r < 3; ++r) {
            const float m0 = M[r][0], m1 = M[r][1];
            M[r][0] =  m0*ct[2] + m1*st[2];
            M[r][1] =  m1*ct[2] - m0*st[2];
            M[r][3] =  fmaf(m0, 800.0f, M[r][3]);
        }
        // T3: alpha=90, a=140, d=-908
        #pragma unroll
        for (int r = 0; r < 3; ++r) {
            const float m0 = M[r][0], m1 = M[r][1], m2 = M[r][2];
            M[r][0] =  m0*ct[3] + m2*st[3];
            M[r][1] =  m2*ct[3] - m0*st[3];
            M[r][2] = -m1;
            M[r][3] =  fmaf(m0, 140.0f, fmaf(m1, 908.0f, M[r][3]));
        }
        // T4: alpha=-96, a=0, d=0
        {
            const float sa = -0.99452190f, ca = -0.10452846f;
            const float t10 = st[4]*ca, t11 = ct[4]*ca, t20 = st[4]*sa, t21 = ct[4]*sa;
            #pragma unroll
            for (int r = 0; r < 3; ++r) {
                const float m0 = M[r][0], m1 = M[r][1], m2 = M[r][2];
                M[r][0] =  m0*ct[4] + m1*t10 + m2*t20;
                M[r][1] = -m0*st[4] + m1*t11 + m2*t21;
                M[r][2] = -m1*sa + m2*ca;
            }
        }
        // T5 pruned: alpha=-65, a=0, d=260
        {
            const float sa = -0.90630779f, ca = 0.42261826f;
            const float t13 = 235.64003f,  t23 = 109.88075f;
            const float t10 = st[5]*ca, t20 = st[5]*sa;
            const float t11 = ct[5]*ca, t21 = ct[5]*sa;

            const float T00 =  M[0][0]*ct[5] + M[0][1]*t10 + M[0][2]*t20;
            const float T01 = -M[0][0]*st[5] + M[0][1]*t11 + M[0][2]*t21;
            const float T02 = -M[0][1]*sa + M[0][2]*ca;
            const float T12 = -M[1][1]*sa + M[1][2]*ca;
            const float T22 = -M[2][1]*sa + M[2][2]*ca;

            res[0] = fmaf(M[0][1], t13, fmaf(M[0][2], t23, M[0][3]));
            res[1] = fmaf(M[1][1], t13, fmaf(M[1][2], t23, M[1][3]));
            res[2] = fmaf(M[2][1], t13, fmaf(M[2][2], t23, M[2][3]));
            res[3] = atan2_deg(-T01, T00);
            res[4] = atan2_deg(T02, sqrtf(fmaf(T00, T00, T01 * T01)));
            res[5] = atan2_deg(-T12, T22);

            risky = (fabsf(T01) < 1e-4f) | (fabsf(T12) < 1e-4f) |
                    (fmaf(T00, T00, T01 * T01) < 1e-6f) |
                    (fmaf(T12, T12, T22 * T22) < 1e-6f);
        }
    } else {
        // generic fallback, pure f32
        float st[6], ct[6];
        #pragma unroll
        for (int i = 0; i < 6; ++i)
            sincosf_deg(K.th0[i] + thf[i], &st[i], &ct[i]);

        float M[3][4];
        {
            const float ca = K.ca[0], sa = K.sa[0];
            M[0][0] = ct[0];      M[0][1] = -st[0];     M[0][2] = 0.0f; M[0][3] = K.a[0];
            M[1][0] = st[0] * ca; M[1][1] = ct[0] * ca; M[1][2] = -sa;  M[1][3] = K.nsd[0];
            M[2][0] = st[0] * sa; M[2][1] = ct[0] * sa; M[2][2] = ca;   M[2][3] = K.cd[0];
        }
        #pragma unroll
        for (int i = 1; i < 6; ++i) {
            const float ca = K.ca[i], sa = K.sa[i];
            const float t00 = ct[i],      t01 = -st[i],     t03 = K.a[i];
            const float t10 = st[i] * ca, t11 = ct[i] * ca, t12 = -sa, t13 = K.nsd[i];
            const float t20 = st[i] * sa, t21 = ct[i] * sa, t22 = ca,  t23 = K.cd[i];
            #pragma unroll
            for (int r = 0; r < 3; ++r) {
                const float m0 = M[r][0], m1 = M[r][1], m2 = M[r][2], m3 = M[r][3];
                M[r][0] = m0 * t00 + m1 * t10 + m2 * t20;
                M[r][1] = m0 * t01 + m1 * t11 + m2 * t21;
                M[r][2] =            m1 * t12 + m2 * t22;
                M[r][3] = m0 * t03 + m1 * t13 + m2 * t23 + m3;
            }
        }
        const float T00 = M[0][0], T01 = M[0][1], T02 = M[0][2];
        const float T12 = M[1][2], T22 = M[2][2];

        res[0] = M[0][3]; res[1] = M[1][3]; res[2] = M[2][3];
        res[3] = atan2_deg(-T01, T00);
        res[4] = atan2_deg(T02, sqrtf(fmaf(T00, T00, T01 * T01)));
        res[5] = atan2_deg(-T12, T22);

        risky = (fabsf(T01) < 1e-4f) | (fabsf(T12) < 1e-4f) |
                (fmaf(T00, T00, T01 * T01) < 1e-6f) |
                (fmaf(T12, T12, T22 * T22) < 1e-6f);
    }
}

__device__ __forceinline__ void dhf32_init(const float* __restrict__ dh, DHF32& K)
{
    if (threadIdx.x < 6) {
        const int i = threadIdx.x;
        const float alp = dh[i * 4 + 1];
        const float d   = dh[i * 4 + 2];
        float sa, ca;
        sincosf_deg(alp, &sa, &ca);   // exact for multiples of 90
        K.a[i] = dh[i * 4 + 0];  K.ca[i] = ca;  K.sa[i] = sa;
        K.nsd[i] = -sa * d;  K.cd[i] = ca * d;
        K.th0[i] = dh[i * 4 + 3];
    }
    if (threadIdx.x == 0) {
        const float e[24] = { 0.f,180.f,-650.f,0.f,  270.f,90.f,0.f,0.f,
                              800.f,0.f,0.f,0.f,     140.f,90.f,-908.f,0.f,
                              0.f,-96.f,0.f,0.f,     0.f,-65.f,260.f,0.f };
        int ok = 1;
        #pragma unroll
        for (int i = 0; i < 24; ++i) ok &= (dh[i] == e[i]);
        K.spec = ok;
    }
}

// ===================== kernel 1: hot path, no f64, no barrier tail ==========
__global__ __launch_bounds__(256)
void fk6_hot(const float* __restrict__ theta,
             const float* __restrict__ dh,
             float* __restrict__ out,
             unsigned long long* __restrict__ masks,  // [ceil(grid*256/64)]
             int B)
{
    __shared__ DHF32 K;
    dhf32_init(dh, K);
    __syncthreads();

    const int t = blockIdx.x * 256 + threadIdx.x;
    const bool valid = (t < B);
    bool risky = false;

    if (valid) {
        const float2* tp = reinterpret_cast<const float2*>(theta + 6ll * t);
        const float2 v01 = tp[0], v23 = tp[1], v45 = tp[2];
        const float thf[6] = { v01.x, v01.y, v23.x, v23.y, v45.x, v45.y };

        float res[6];
        fk_hot(thf, K, res, risky);

        float2* op = reinterpret_cast<float2*>(out + 6ll * t);
        op[0] = make_float2(res[0], res[1]);
        op[1] = make_float2(res[2], res[3]);
        op[2] = make_float2(res[4], res[5]);
    }

    // Wave-level risky record: one u64 store per wave, always written.
    const unsigned long long m = __ballot(risky);
    if ((threadIdx.x & 63) == 0)
        masks[t >> 6] = m;
}

// ===================== kernel 2: f64 redo of flagged bits ===================
struct DHF64 { double a[6], ca[6], sa[6], nsd[6], cd[6], th0[6]; };

__device__ __forceinline__ void fix_elem(const float* __restrict__ theta,
                                         float* __restrict__ out,
                                         const DHF64& K, long long b)
{
    const float2* tp = reinterpret_cast<const float2*>(theta + 6ll * b);
    const float2 v01 = tp[0], v23 = tp[1], v45 = tp[2];
    const double th[6] = { (double)v01.x, (double)v01.y,
                           (double)v23.x, (double)v23.y,
                           (double)v45.x, (double)v45.y };

    double dst[6], dct[6];
    #pragma unroll
    for (int i = 0; i < 6; ++i)
        sincos_deg(K.th0[i] + th[i], &dst[i], &dct[i]);

    double D[3][4];
    {
        const double ca = K.ca[0], sa = K.sa[0];
        D[0][0] = dct[0];      D[0][1] = -dst[0];     D[0][2] = 0.0; D[0][3] = K.a[0];
        D[1][0] = dst[0] * ca; D[1][1] = dct[0] * ca; D[1][2] = -sa; D[1][3] = K.nsd[0];
        D[2][0] = dst[0] * sa; D[2][1] = dct[0] * sa; D[2][2] = ca;  D[2][3] = K.cd[0];
    }
    #pragma unroll
    for (int i = 1; i < 6; ++i) {
        const double ca = K.ca[i], sa = K.sa[i];
        const double t00 = dct[i],      t01 = -dst[i],     t03 = K.a[i];
        const double t10 = dst[i] * ca, t11 = dct[i] * ca, t12 = -sa, t13 = K.nsd[i];
        const double t20 = dst[i] * sa, t21 = dct[i] * sa, t22 = ca,  t23 = K.cd[i];
        #pragma unroll
        for (int r = 0; r < 3; ++r) {
            const double m0 = D[r][0], m1 = D[r][1], m2 = D[r][2], m3 = D[r][3];
            D[r][0] = m0 * t00 + m1 * t10 + m2 * t20;
            D[r][1] = m0 * t01 + m1 * t11 + m2 * t21;
            D[r][2] =            m1 * t12 + m2 * t22;
            D[r][3] = m0 * t03 + m1 * t13 + m2 * t23 + m3;
        }
    }
    const float d00 = (float)D[0][0], d01 = (float)D[0][1], d02 = (float)D[0][2];
    const float d12 = (float)D[1][2], d22 = (float)D[2][2];

    float A  = atan2f(-d01, d00) * DEG_F;
    float Bd = atan2f(d02, sqrtf(fmaf(d00, d00, d01 * d01))) * DEG_F;
    float C  = atan2f(-d12, d22) * DEG_F;
    if (fabs(D[1][2]) <= TINY_D && fabs(D[2][2]) <= TINY_D) {
        Bd = atan2f(d02, d22) * DEG_F;
        A  = atan2f((float)D[1][0], (float)D[1][1]) * DEG_F;
        C  = 0.0f;
    }

    float2* op = reinterpret_cast<float2*>(out + 6ll * b);
    op[0] = make_float2((float)D[0][3], (float)D[1][3]);
    op[1] = make_float2((float)D[2][3], A);
    op[2] = make_float2(Bd, C);
}

__global__ void fk6_fixb(const float* __restrict__ theta,
                         const float* __restrict__ dh,
                         float* __restrict__ out,
                         const unsigned long long* __restrict__ masks,
                         int nwaves)
{
    __shared__ DHF64 K;
    if (threadIdx.x < 6) {
        const int i = threadIdx.x;
        const double alp = (double)dh[i * 4 + 1];
        const double d   = (double)dh[i * 4 + 2];
        double sa, ca;
        sincos_deg(alp, &sa, &ca);
        K.a[i] = (double)dh[i * 4 + 0];  K.ca[i] = ca;  K.sa[i] = sa;
        K.nsd[i] = -sa * d;  K.cd[i] = ca * d;
        K.th0[i] = (double)dh[i * 4 + 3];
    }
    __syncthreads();

    for (int w = blockIdx.x * blockDim.x + threadIdx.x; w < nwaves;
         w += gridDim.x * blockDim.x) {
        unsigned long long m = masks[w];
        while (m) {
            const int l = __ffsll((unsigned long long)m) - 1;
            m &= m - 1;
            fix_elem(theta, out, K, (long long)w * 64 + l);
        }
    }
}

// ===================== fallback: combined (R11 semantics) ===================
__global__ __launch_bounds__(256)
void fk6_combined(const float* __restrict__ theta,
                  const float* __restrict__ dh,
                  float* __restrict__ out,
                  int B)
{
    __shared__ DHF32 K;
    __shared__ DHF64 K64;
    dhf32_init(dh, K);
    if (threadIdx.x >= 64 && threadIdx.x < 70) {
        const int i = threadIdx.x - 64;
        const double alp = (double)dh[i * 4 + 1];
        const double d   = (double)dh[i * 4 + 2];
        double sa, ca;
        sincos_deg(alp, &sa, &ca);
        K64.a[i] = (double)dh[i * 4 + 0];  K64.ca[i] = ca;  K64.sa[i] = sa;
        K64.nsd[i] = -sa * d;  K64.cd[i] = ca * d;
        K64.th0[i] = (double)dh[i * 4 + 3];
    }
    __syncthreads();

    const int t = blockIdx.x * 256 + threadIdx.x;
    if (t >= B) return;

    const float2* tp = reinterpret_cast<const float2*>(theta + 6ll * t);
    const float2 v01 = tp[0], v23 = tp[1], v45 = tp[2];
    const float thf[6] = { v01.x, v01.y, v23.x, v23.y, v45.x, v45.y };

    float res[6];
    bool risky;
    fk_hot(thf, K, res, risky);

    float2* op = reinterpret_cast<float2*>(out + 6ll * t);
    op[0] = make_float2(res[0], res[1]);
    op[1] = make_float2(res[2], res[3]);
    op[2] = make_float2(res[4], res[5]);

    if (__builtin_expect(risky, 0))
        fix_elem(theta, out, K64, t);
}

extern "C" void kernel_launch(void* const* d_in, const int* in_sizes, int n_in,
                              void* d_out, int out_size, void* d_ws, size_t ws_size,
                              hipStream_t stream) {
    const float* theta = (const float*)d_in[0];   // (B, 6) f32
    const float* dh    = (const float*)d_in[1];   // (6, 4) f32
    float* out = (float*)d_out;                   // (B, 6) f32

    const int B = in_sizes[0] / 6;
    const int block = 256;
    const int grid = (B + block - 1) / block;
    const int nwaves = grid * (block / 64);       // mask slots (all written)

    if (ws_size >= (size_t)nwaves * 8) {
        unsigned long long* masks = (unsigned long long*)d_ws;
        fk6_hot<<<grid, block, 0, stream>>>(theta, dh, out, masks, B);
        fk6_fixb<<<64, 256, 0, stream>>>(theta, dh, out, masks, nwaves);
    } else {
        fk6_combined<<<grid, block, 0, stream>>>(theta, dh, out, B);
    }
}

// Round 13
// 24.221 us; speedup vs baseline: 1.2083x; 1.2083x over previous
//
#include <hip/hip_runtime.h>
#include <math.h>

// Forward kinematics, 6-joint DH chain, B=1048576.
// R13: single kernel (R11 body) + LDS-staged fully-coalesced global I/O.
// Evidence: R11 (instr/2 -> null), R12 (VGPR/occupancy fix -> null) exonerate
// VALU and registers. The constant across all ~22.7us kernels: stride-24B
// float2 global access (each 64-lane ld/st touches 24 cachelines at 1/3
// utilization -> ~3x cacheline amplification). This round: block stages
// 256x6 floats through LDS; global traffic becomes 3 coalesced float2
// ld + 3 st per thread (512B/instr, full lines). Risky lanes overwrite
// their own LDS result slots with the exact f64 redo BEFORE the store
// barrier (no global-write race, no extra pass).

#define RAD_D  (3.141592653589793 / 180.0)
#define RAD_F  0.017453292519943295f
#define DEG_F  57.29577951308232f
#define TINY_D 1e-6

// ---------- f64 sincos of degrees (Cephes, ~1ulp) ----------
__device__ __forceinline__ void sincos_deg(double xdeg, double* s, double* c)
{
    const double qf = rint(xdeg * (1.0 / 90.0));
    const double r  = fma(qf, -90.0, xdeg) * RAD_D;
    const int q = ((int)qf) & 3;
    const double z = r * r;

    double sp = 1.58962301576546568060e-10;
    sp = fma(sp, z, -2.50507477628578072866e-8);
    sp = fma(sp, z,  2.75573136213857245213e-6);
    sp = fma(sp, z, -1.98412698295895385996e-4);
    sp = fma(sp, z,  8.33333333332211858878e-3);
    sp = fma(sp, z, -1.66666666666666307295e-1);
    const double sr = fma(r * z, sp, r);

    double cp = -1.13585365213876817300e-11;
    cp = fma(cp, z,  2.08757008419747316778e-9);
    cp = fma(cp, z, -2.75573141792967388112e-7);
    cp = fma(cp, z,  2.48015872888517179954e-5);
    cp = fma(cp, z, -1.38888888888730564116e-3);
    cp = fma(cp, z,  4.16666666666665929218e-2);
    const double cr = fma(z * z, cp, fma(z, -0.5, 1.0));

    double ss = (q & 1) ? cr : sr;
    double cc = (q & 1) ? sr : cr;
    ss = (q & 2)       ? -ss : ss;
    cc = ((q + 1) & 2) ? -cc : cc;
    *s = ss; *c = cc;
}

// ---------- f32 sincos of degrees ----------
__device__ __forceinline__ void sincosf_deg(float xdeg, float* s, float* c)
{
    const float qf = rintf(xdeg * (1.0f / 90.0f));
    const float r  = fmaf(qf, -90.0f, xdeg) * RAD_F;
    const int q = ((int)qf) & 3;
    const float z = r * r;

    float sp = -1.9515295891e-4f;
    sp = fmaf(sp, z,  8.3321608736e-3f);
    sp = fmaf(sp, z, -1.6666654611e-1f);
    const float sr = fmaf(r * z, sp, r);

    float cp =  2.443315711809948e-5f;
    cp = fmaf(cp, z, -1.388731625493765e-3f);
    cp = fmaf(cp, z,  4.166664568298827e-2f);
    const float cr = fmaf(z * z, cp, fmaf(z, -0.5f, 1.0f));

    float ss = (q & 1) ? cr : sr;
    float cc = (q & 1) ? sr : cr;
    ss = (q & 2)       ? -ss : ss;
    cc = ((q + 1) & 2) ? -cc : cc;
    *s = ss; *c = cc;
}

// ---------- f32 atan2 in DEGREES (poly + hw rcp) ----------
__device__ __forceinline__ float atan2_deg(float y, float x)
{
    const float ay = fabsf(y), ax = fabsf(x);
    const float mn = fminf(ay, ax), mx = fmaxf(ay, ax);
    const float r  = mn * __builtin_amdgcn_rcpf(mx);
    const float z  = r * r;
    float p = -0.671575f;
    p = fmaf(p, z,  3.016813f);
    p = fmaf(p, z, -6.671107f);
    p = fmaf(p, z, 11.089241f);
    p = fmaf(p, z, -19.057917f);
    p = fmaf(p, z, 57.294477f);
    float a = r * p;
    a = (ay > ax)   ? 90.0f  - a : a;
    a = (x < 0.0f)  ? 180.0f - a : a;
    return copysignf(a, y);
}

struct DHF32 { float a[6], ca[6], sa[6], nsd[6], cd[6], th0[6]; int spec; };
struct DHF64 { double a[6], ca[6], sa[6], nsd[6], cd[6], th0[6]; };

// ---------- f32 compute: res[6] + risky ----------
__device__ __forceinline__ void fk_hot(const float thf[6], const DHF32& K,
                                       float res[6], bool& risky)
{
    if (K.spec) {
        float st[6], ct[6];
        #pragma unroll
        for (int i = 0; i < 6; ++i)
            sincosf_deg(thf[i], &st[i], &ct[i]);

        float M[3][4];
        M[0][0] =  ct[0]*ct[1];  M[0][1] = -ct[0]*st[1];  M[0][2] = st[0];  M[0][3] =  270.0f*ct[0];
        M[1][0] = -st[0]*ct[1];  M[1][1] =  st[0]*st[1];  M[1][2] = ct[0];  M[1][3] = -270.0f*st[0];
        M[2][0] = -st[1];        M[2][1] = -ct[1];        M[2][2] = 0.0f;   M[2][3] =  650.0f;

        #pragma unroll
        for (int r = 0; r < 3; ++r) {            // T2: alpha=0, a=800
            const float m0 = M[r][0], m1 = M[r][1];
            M[r][0] =  m0*ct[2] + m1*st[2];
            M[r][1] =  m1*ct[2] - m0*st[2];
            M[r][3] =  fmaf(m0, 800.0f, M[r][3]);
        }
        #pragma unroll
        for (int r = 0; r < 3; ++r) {            // T3: alpha=90, a=140, d=-908
            const float m0 = M[r][0], m1 = M[r][1], m2 = M[r][2];
            M[r][0] =  m0*ct[3] + m2*st[3];
            M[r][1] =  m2*ct[3] - m0*st[3];
            M[r][2] = -m1;
            M[r][3] =  fmaf(m0, 140.0f, fmaf(m1, 908.0f, M[r][3]));
        }
        {                                        // T4: alpha=-96
            const float sa = -0.99452190f, ca = -0.10452846f;
            const float t10 = st[4]*ca, t11 = ct[4]*ca, t20 = st[4]*sa, t21 = ct[4]*sa;
            #pragma unroll
            for (int r = 0; r < 3; ++r) {
                const float m0 = M[r][0], m1 = M[r][1], m2 = M[r][2];
                M[r][0] =  m0*ct[4] + m1*t10 + m2*t20;
                M[r][1] = -m0*st[4] + m1*t11 + m2*t21;
                M[r][2] = -m1*sa + m2*ca;
            }
        }
        {                                        // T5 pruned: alpha=-65, d=260
            const float sa = -0.90630779f, ca = 0.42261826f;
            const float t13 = 235.64003f,  t23 = 109.88075f;
            const float t10 = st[5]*ca, t20 = st[5]*sa;
            const float t11 = ct[5]*ca, t21 = ct[5]*sa;

            const float T00 =  M[0][0]*ct[5] + M[0][1]*t10 + M[0][2]*t20;
            const float T01 = -M[0][0]*st[5] + M[0][1]*t11 + M[0][2]*t21;
            const float T02 = -M[0][1]*sa + M[0][2]*ca;
            const float T12 = -M[1][1]*sa + M[1][2]*ca;
            const float T22 = -M[2][1]*sa + M[2][2]*ca;

            res[0] = fmaf(M[0][1], t13, fmaf(M[0][2], t23, M[0][3]));
            res[1] = fmaf(M[1][1], t13, fmaf(M[1][2], t23, M[1][3]));
            res[2] = fmaf(M[2][1], t13, fmaf(M[2][2], t23, M[2][3]));
            res[3] = atan2_deg(-T01, T00);
            res[4] = atan2_deg(T02, sqrtf(fmaf(T00, T00, T01 * T01)));
            res[5] = atan2_deg(-T12, T22);

            risky = (fabsf(T01) < 1e-4f) | (fabsf(T12) < 1e-4f) |
                    (fmaf(T00, T00, T01 * T01) < 1e-6f) |
                    (fmaf(T12, T12, T22 * T22) < 1e-6f);
        }
    } else {
        float st[6], ct[6];
        #pragma unroll
        for (int i = 0; i < 6; ++i)
            sincosf_deg(K.th0[i] + thf[i], &st[i], &ct[i]);

        float M[3][4];
        {
            const float ca = K.ca[0], sa = K.sa[0];
            M[0][0] = ct[0];      M[0][1] = -st[0];     M[0][2] = 0.0f; M[0][3] = K.a[0];
            M[1][0] = st[0] * ca; M[1][1] = ct[0] * ca; M[1][2] = -sa;  M[1][3] = K.nsd[0];
            M[2][0] = st[0] * sa; M[2][1] = ct[0] * sa; M[2][2] = ca;   M[2][3] = K.cd[0];
        }
        #pragma unroll
        for (int i = 1; i < 6; ++i) {
            const float ca = K.ca[i], sa = K.sa[i];
            const float t00 = ct[i],      t01 = -st[i],     t03 = K.a[i];
            const float t10 = st[i] * ca, t11 = ct[i] * ca, t12 = -sa, t13 = K.nsd[i];
            const float t20 = st[i] * sa, t21 = ct[i] * sa, t22 = ca,  t23 = K.cd[i];
            #pragma unroll
            for (int r = 0; r < 3; ++r) {
                const float m0 = M[r][0], m1 = M[r][1], m2 = M[r][2], m3 = M[r][3];
                M[r][0] = m0 * t00 + m1 * t10 + m2 * t20;
                M[r][1] = m0 * t01 + m1 * t11 + m2 * t21;
                M[r][2] =            m1 * t12 + m2 * t22;
                M[r][3] = m0 * t03 + m1 * t13 + m2 * t23 + m3;
            }
        }
        const float T00 = M[0][0], T01 = M[0][1], T02 = M[0][2];
        const float T12 = M[1][2], T22 = M[2][2];

        res[0] = M[0][3]; res[1] = M[1][3]; res[2] = M[2][3];
        res[3] = atan2_deg(-T01, T00);
        res[4] = atan2_deg(T02, sqrtf(fmaf(T00, T00, T01 * T01)));
        res[5] = atan2_deg(-T12, T22);

        risky = (fabsf(T01) < 1e-4f) | (fabsf(T12) < 1e-4f) |
                (fmaf(T00, T00, T01 * T01) < 1e-6f) |
                (fmaf(T12, T12, T22 * T22) < 1e-6f);
    }
}

// ---------- exact f64 redo -> res[6] (R3-validated math) ----------
__device__ __forceinline__ void fix_res(const float thf[6], const DHF64& K,
                                        float res[6])
{
    double dst[6], dct[6];
    #pragma unroll
    for (int i = 0; i < 6; ++i)
        sincos_deg(K.th0[i] + (double)thf[i], &dst[i], &dct[i]);

    double D[3][4];
    {
        const double ca = K.ca[0], sa = K.sa[0];
        D[0][0] = dct[0];      D[0][1] = -dst[0];     D[0][2] = 0.0; D[0][3] = K.a[0];
        D[1][0] = dst[0] * ca; D[1][1] = dct[0] * ca; D[1][2] = -sa; D[1][3] = K.nsd[0];
        D[2][0] = dst[0] * sa; D[2][1] = dct[0] * sa; D[2][2] = ca;  D[2][3] = K.cd[0];
    }
    #pragma unroll
    for (int i = 1; i < 6; ++i) {
        const double ca = K.ca[i], sa = K.sa[i];
        const double t00 = dct[i],      t01 = -dst[i],     t03 = K.a[i];
        const double t10 = dst[i] * ca, t11 = dct[i] * ca, t12 = -sa, t13 = K.nsd[i];
        const double t20 = dst[i] * sa, t21 = dct[i] * sa, t22 = ca,  t23 = K.cd[i];
        #pragma unroll
        for (int r = 0; r < 3; ++r) {
            const double m0 = D[r][0], m1 = D[r][1], m2 = D[r][2], m3 = D[r][3];
            D[r][0] = m0 * t00 + m1 * t10 + m2 * t20;
            D[r][1] = m0 * t01 + m1 * t11 + m2 * t21;
            D[r][2] =            m1 * t12 + m2 * t22;
            D[r][3] = m0 * t03 + m1 * t13 + m2 * t23 + m3;
        }
    }
    const float d00 = (float)D[0][0], d01 = (float)D[0][1], d02 = (float)D[0][2];
    const float d12 = (float)D[1][2], d22 = (float)D[2][2];

    float A  = atan2f(-d01, d00) * DEG_F;
    float Bd = atan2f(d02, sqrtf(fmaf(d00, d00, d01 * d01))) * DEG_F;
    float C  = atan2f(-d12, d22) * DEG_F;
    if (fabs(D[1][2]) <= TINY_D && fabs(D[2][2]) <= TINY_D) {
        Bd = atan2f(d02, d22) * DEG_F;
        A  = atan2f((float)D[1][0], (float)D[1][1]) * DEG_F;
        C  = 0.0f;
    }
    res[0] = (float)D[0][3]; res[1] = (float)D[1][3]; res[2] = (float)D[2][3];
    res[3] = A; res[4] = Bd; res[5] = C;
}

__device__ __forceinline__ void init_consts(const float* __restrict__ dh,
                                            DHF32& K, DHF64& K64)
{
    if (threadIdx.x < 6) {
        const int i = threadIdx.x;
        const float alp = dh[i * 4 + 1];
        const float d   = dh[i * 4 + 2];
        float sa, ca;
        sincosf_deg(alp, &sa, &ca);
        K.a[i] = dh[i * 4 + 0];  K.ca[i] = ca;  K.sa[i] = sa;
        K.nsd[i] = -sa * d;  K.cd[i] = ca * d;
        K.th0[i] = dh[i * 4 + 3];
    }
    if (threadIdx.x >= 64 && threadIdx.x < 70) {
        const int i = threadIdx.x - 64;
        const double alp = (double)dh[i * 4 + 1];
        const double d   = (double)dh[i * 4 + 2];
        double sa, ca;
        sincos_deg(alp, &sa, &ca);
        K64.a[i] = (double)dh[i * 4 + 0];  K64.ca[i] = ca;  K64.sa[i] = sa;
        K64.nsd[i] = -sa * d;  K64.cd[i] = ca * d;
        K64.th0[i] = (double)dh[i * 4 + 3];
    }
    if (threadIdx.x == 0) {
        const float e[24] = { 0.f,180.f,-650.f,0.f,  270.f,90.f,0.f,0.f,
                              800.f,0.f,0.f,0.f,     140.f,90.f,-908.f,0.f,
                              0.f,-96.f,0.f,0.f,     0.f,-65.f,260.f,0.f };
        int ok = 1;
        #pragma unroll
        for (int i = 0; i < 24; ++i) ok &= (dh[i] == e[i]);
        K.spec = ok;
    }
}

// ===================== the kernel =====================
__global__ __launch_bounds__(256)
void fk6_r13(const float* __restrict__ theta,
             const float* __restrict__ dh,
             float* __restrict__ out,
             int B)
{
    __shared__ DHF32 K;
    __shared__ DHF64 K64;
    __shared__ float2 sbuf[768];      // 256 elems x 3 float2 = 6KB

    init_consts(dh, K, K64);

    const int tid = threadIdx.x;
    const long long blk = blockIdx.x;
    const long long e0  = blk * 256;              // first element of block

    if (e0 + 256 <= (long long)B) {
        // ---- coalesced load: 3 x (64 lanes x 8B contiguous) ----
        const float2* gin = reinterpret_cast<const float2*>(theta) + blk * 768;
        const float2 l0 = gin[tid];
        const float2 l1 = gin[tid + 256];
        const float2 l2 = gin[tid + 512];
        sbuf[tid]       = l0;
        sbuf[tid + 256] = l1;
        sbuf[tid + 512] = l2;
        __syncthreads();   // also covers init_consts

        // each thread reads ITS element's 6 floats (slots 3t..3t+2)
        const float2 a = sbuf[3 * tid];
        const float2 b = sbuf[3 * tid + 1];
        const float2 c = sbuf[3 * tid + 2];
        const float thf[6] = { a.x, a.y, b.x, b.y, c.x, c.y };

        float res[6];
        bool risky;
        fk_hot(thf, K, res, risky);

        if (__builtin_expect(risky, 0))
            fix_res(thf, K64, res);   // overwrite res with exact f64 values

        // write result into own slots (no cross-thread hazard: slot 3t+j is
        // read-before/written-after only by thread t)
        sbuf[3 * tid]     = make_float2(res[0], res[1]);
        sbuf[3 * tid + 1] = make_float2(res[2], res[3]);
        sbuf[3 * tid + 2] = make_float2(res[4], res[5]);
        __syncthreads();

        // ---- coalesced store ----
        float2* gout = reinterpret_cast<float2*>(out) + blk * 768;
        gout[tid]       = sbuf[tid];
        gout[tid + 256] = sbuf[tid + 256];
        gout[tid + 512] = sbuf[tid + 512];
    } else {
        // partial tail block (not hit for B=1048576): direct scalar path
        __syncthreads();
        const long long t = e0 + tid;
        if (t < B) {
            const float2* tp = reinterpret_cast<const float2*>(theta + 6ll * t);
            const float2 v01 = tp[0], v23 = tp[1], v45 = tp[2];
            const float thf[6] = { v01.x, v01.y, v23.x, v23.y, v45.x, v45.y };
            float res[6];
            bool risky;
            fk_hot(thf, K, res, risky);
            if (risky) fix_res(thf, K64, res);
            float2* op = reinterpret_cast<float2*>(out + 6ll * t);
            op[0] = make_float2(res[0], res[1]);
            op[1] = make_float2(res[2], res[3]);
            op[2] = make_float2(res[4], res[5]);
        }
    }
}

extern "C" void kernel_launch(void* const* d_in, const int* in_sizes, int n_in,
                              void* d_out, int out_size, void* d_ws, size_t ws_size,
                              hipStream_t stream) {
    const float* theta = (const float*)d_in[0];   // (B, 6) f32
    const float* dh    = (const float*)d_in[1];   // (6, 4) f32
    float* out = (float*)d_out;                   // (B, 6) f32

    const int B = in_sizes[0] / 6;
    const int block = 256;
    const int grid = (B + block - 1) / block;
    fk6_r13<<<grid, block, 0, stream>>>(theta, dh, out, B);
}